// Round 8
// baseline (76.474 us; speedup 1.0000x reference)
//
#include <hip/hip_runtime.h>

#define VOCAB 100000
#define D     300
#define B     256
#define L     1000
#define H     512
#define C     5

#define SPLIT 10
#define CHUNK (L / SPLIT)   // 100 rows per gather block
#define D4f   (D / 4)       // 75 float4 per row

// ws layout (floats)
#define WS_PARTIAL 0
#define WS_AVG     (B * SPLIT * D)          // 768000
#define WS_H1      (WS_AVG + B * D)         // +76800
#define WS_H2      (WS_H1 + B * H)          // +131072 -> ~4.4 MB total

// ---------------------------------------------------------------------------
// K1: gather + partial sum — proven kernel, verbatim (BW-bound on the L3
// read fabric, ~50-55 us for 307 MB of random L3-resident rows).
// ---------------------------------------------------------------------------
__global__ __launch_bounds__(320) void gather_sum_kernel(
    const float* __restrict__ emb, const int* __restrict__ docs,
    float* __restrict__ partial) {
  const int b = blockIdx.x;
  const int s = blockIdx.y;
  const int t = threadIdx.x;
  const int rg = t / 80;
  const int lane = t - rg * 80;

  __shared__ int sidx[CHUNK];
  if (t < CHUNK) sidx[t] = docs[b * L + s * CHUNK + t];
  __syncthreads();

  float ax = 0.f, ay = 0.f, az = 0.f, aw = 0.f;
  if (lane < D4f) {
#pragma unroll 5
    for (int l = 0; l < CHUNK; l += 4) {
      const int idx = sidx[l + rg];
      const float4 v =
          reinterpret_cast<const float4*>(emb + (size_t)idx * D)[lane];
      ax += v.x; ay += v.y; az += v.z; aw += v.w;
    }
  }

  __shared__ float4 sred[3][D4f];
  if (rg > 0 && lane < D4f) sred[rg - 1][lane] = make_float4(ax, ay, az, aw);
  __syncthreads();
  if (rg == 0 && lane < D4f) {
#pragma unroll
    for (int g = 0; g < 3; ++g) {
      const float4 v = sred[g][lane];
      ax += v.x; ay += v.y; az += v.z; aw += v.w;
    }
    reinterpret_cast<float4*>(partial + (size_t)(b * SPLIT + s) * D)[lane] =
        make_float4(ax, ay, az, aw);
  }
}

// ---------------------------------------------------------------------------
// K2: avg[b] = (sum of 10 partials) / len[b]. Reads 3 MB ONCE (vs 16x when
// folded into l1 = 49 MB saved). grid 256 x 128 thr.
// ---------------------------------------------------------------------------
__global__ __launch_bounds__(128) void avg_kernel(
    const float* __restrict__ partial, const int* __restrict__ dlen,
    float* __restrict__ avg) {
  const int b = blockIdx.x;
  const int t = threadIdx.x;
  if (t < D4f) {
    const float4* p = reinterpret_cast<const float4*>(partial) +
                      (size_t)b * (SPLIT * D4f) + t;
    float4 v[SPLIT];
#pragma unroll
    for (int s = 0; s < SPLIT; ++s) v[s] = p[s * D4f];
    float ax = 0.f, ay = 0.f, az = 0.f, aw = 0.f;
#pragma unroll
    for (int s = 0; s < SPLIT; ++s) {
      ax += v[s].x; ay += v[s].y; az += v[s].z; aw += v[s].w;
    }
    const float inv = 1.f / (float)dlen[b];
    reinterpret_cast<float4*>(avg + (size_t)b * D)[t] =
        make_float4(ax * inv, ay * inv, az * inv, aw * inv);
  }
}

// ---------------------------------------------------------------------------
// K3: h1 = relu(avg @ W1 + b1). grid (16 doc-tiles, 16 col-tiles) x 1024.
// W1 slab + avg tile staged to LDS (few independent global loads/thread);
// compute reads from LDS. Thread = (doc 16, cg 8 [4 cols], ks 8 [K-slice]).
// ---------------------------------------------------------------------------
__global__ __launch_bounds__(1024) void l1_kernel(
    const float* __restrict__ avg, const float* __restrict__ W1,
    const float* __restrict__ b1, float* __restrict__ h1) {
  const int dq = blockIdx.x;
  const int cq = blockIdx.y;
  const int t = threadIdx.x;

  __shared__ float4 s_avg[16][D4f];          // 19200 B
  __shared__ float  s_w[D][32];              // 38400 B
  __shared__ float  s_comb[8][16][32];       // 16384 B

  for (int o = t; o < D * 8; o += 1024) {
    const int k = o >> 3, c4 = o & 7;
    *reinterpret_cast<float4*>(&s_w[k][c4 * 4]) =
        *reinterpret_cast<const float4*>(W1 + (size_t)k * H + cq * 32 + c4 * 4);
  }
  for (int o = t; o < 16 * D4f; o += 1024) {
    const int doc = o / D4f, c4 = o - doc * D4f;
    s_avg[doc][c4] =
        reinterpret_cast<const float4*>(avg + (size_t)(dq * 16 + doc) * D)[c4];
  }
  __syncthreads();

  {
    const int doc = t & 15;
    const int cg = (t >> 4) & 7;
    const int ks = t >> 7;                      // 8 K-slices of 10/9 float4
    const int nf4 = (ks < 3) ? 10 : 9;
    const int o4 = (ks < 3) ? 10 * ks : 30 + 9 * (ks - 3);
    float ax = 0.f, ay = 0.f, az = 0.f, aw = 0.f;
    for (int j = 0; j < nf4; ++j) {
      const float4 x4 = s_avg[doc][o4 + j];
      const int k = 4 * (o4 + j);
      const float4 w0 = *reinterpret_cast<const float4*>(&s_w[k + 0][cg * 4]);
      const float4 w1 = *reinterpret_cast<const float4*>(&s_w[k + 1][cg * 4]);
      const float4 w2 = *reinterpret_cast<const float4*>(&s_w[k + 2][cg * 4]);
      const float4 w3 = *reinterpret_cast<const float4*>(&s_w[k + 3][cg * 4]);
      ax += x4.x * w0.x + x4.y * w1.x + x4.z * w2.x + x4.w * w3.x;
      ay += x4.x * w0.y + x4.y * w1.y + x4.z * w2.y + x4.w * w3.y;
      az += x4.x * w0.z + x4.y * w1.z + x4.z * w2.z + x4.w * w3.z;
      aw += x4.x * w0.w + x4.y * w1.w + x4.z * w2.w + x4.w * w3.w;
    }
    *reinterpret_cast<float4*>(&s_comb[ks][doc][cg * 4]) =
        make_float4(ax, ay, az, aw);
  }
  __syncthreads();

  if (t < 512) {
    const int dd = t >> 5, col = t & 31;
    float v = b1[cq * 32 + col];
#pragma unroll
    for (int s = 0; s < 8; ++s) v += s_comb[s][dd][col];
    h1[(size_t)(dq * 16 + dd) * H + cq * 32 + col] = fmaxf(v, 0.f);
  }
}

// ---------------------------------------------------------------------------
// K4: h2 = relu(h1 @ W2 + b2). Same structure, K = 512 (8 slices x 16 f4).
// ---------------------------------------------------------------------------
__global__ __launch_bounds__(1024) void l2_kernel(
    const float* __restrict__ h1, const float* __restrict__ W2,
    const float* __restrict__ b2, float* __restrict__ h2) {
  const int dq = blockIdx.x;
  const int cq = blockIdx.y;
  const int t = threadIdx.x;

  __shared__ float4 s_x[16][H / 4];          // 32768 B
  __shared__ float  s_w[H][32];              // 65536 B
  __shared__ float  s_comb[8][16][32];       // 16384 B

  for (int o = t; o < H * 8; o += 1024) {
    const int k = o >> 3, c4 = o & 7;
    *reinterpret_cast<float4*>(&s_w[k][c4 * 4]) =
        *reinterpret_cast<const float4*>(W2 + (size_t)k * H + cq * 32 + c4 * 4);
  }
  for (int o = t; o < 16 * (H / 4); o += 1024) {
    const int doc = o >> 7, c4 = o & 127;
    s_x[doc][c4] =
        reinterpret_cast<const float4*>(h1 + (size_t)(dq * 16 + doc) * H)[c4];
  }
  __syncthreads();

  {
    const int doc = t & 15;
    const int cg = (t >> 4) & 7;
    const int ks = t >> 7;
    float ax = 0.f, ay = 0.f, az = 0.f, aw = 0.f;
    for (int j = 0; j < 16; ++j) {
      const int kk = ks * 16 + j;
      const float4 x4 = s_x[doc][kk];
      const int k = 4 * kk;
      const float4 w0 = *reinterpret_cast<const float4*>(&s_w[k + 0][cg * 4]);
      const float4 w1 = *reinterpret_cast<const float4*>(&s_w[k + 1][cg * 4]);
      const float4 w2 = *reinterpret_cast<const float4*>(&s_w[k + 2][cg * 4]);
      const float4 w3 = *reinterpret_cast<const float4*>(&s_w[k + 3][cg * 4]);
      ax += x4.x * w0.x + x4.y * w1.x + x4.z * w2.x + x4.w * w3.x;
      ay += x4.x * w0.y + x4.y * w1.y + x4.z * w2.y + x4.w * w3.y;
      az += x4.x * w0.z + x4.y * w1.z + x4.z * w2.z + x4.w * w3.z;
      aw += x4.x * w0.w + x4.y * w1.w + x4.z * w2.w + x4.w * w3.w;
    }
    *reinterpret_cast<float4*>(&s_comb[ks][doc][cg * 4]) =
        make_float4(ax, ay, az, aw);
  }
  __syncthreads();

  if (t < 512) {
    const int dd = t >> 5, col = t & 31;
    float v = b2[cq * 32 + col];
#pragma unroll
    for (int s = 0; s < 8; ++s) v += s_comb[s][dd][col];
    h2[(size_t)(dq * 16 + dd) * H + cq * 32 + col] = fmaxf(v, 0.f);
  }
}

// ---------------------------------------------------------------------------
// K5: out = h2 @ W3 + b3. 256 blocks x 64 threads; W3 is 10 KB (cache-hot).
// ---------------------------------------------------------------------------
__global__ __launch_bounds__(64) void head_kernel(
    const float* __restrict__ h2, const float* __restrict__ W3,
    const float* __restrict__ b3, float* __restrict__ out) {
  const int b = blockIdx.x;
  const int l = threadIdx.x;
  float acc[C] = {0.f, 0.f, 0.f, 0.f, 0.f};
#pragma unroll
  for (int i = 0; i < H / 64; ++i) {
    const int h = i * 64 + l;
    const float v = h2[(size_t)b * H + h];
#pragma unroll
    for (int c = 0; c < C; ++c) acc[c] += v * W3[h * C + c];
  }
#pragma unroll
  for (int c = 0; c < C; ++c) {
    float a = acc[c];
#pragma unroll
    for (int off = 32; off > 0; off >>= 1) a += __shfl_down(a, off);
    if (l == 0) out[b * C + c] = a + b3[c];
  }
}

// ---------------------------------------------------------------------------
extern "C" void kernel_launch(void* const* d_in, const int* in_sizes, int n_in,
                              void* d_out, int out_size, void* d_ws,
                              size_t ws_size, hipStream_t stream) {
  const float* emb  = (const float*)d_in[0];
  const float* W1   = (const float*)d_in[1];
  const float* b1   = (const float*)d_in[2];
  const float* W2   = (const float*)d_in[3];
  const float* b2   = (const float*)d_in[4];
  const float* W3   = (const float*)d_in[5];
  const float* b3   = (const float*)d_in[6];
  const int*   docs = (const int*)d_in[7];
  const int*   dlen = (const int*)d_in[8];
  float* out = (float*)d_out;

  float* ws = (float*)d_ws;
  float* partial = ws + WS_PARTIAL;
  float* avg = ws + WS_AVG;
  float* h1  = ws + WS_H1;
  float* h2  = ws + WS_H2;

  dim3 g1(B, SPLIT);
  gather_sum_kernel<<<g1, 320, 0, stream>>>(emb, docs, partial);
  avg_kernel<<<B, 128, 0, stream>>>(partial, dlen, avg);
  dim3 gl(16, 16);
  l1_kernel<<<gl, 1024, 0, stream>>>(avg, W1, b1, h1);
  l2_kernel<<<gl, 1024, 0, stream>>>(h1, W2, b2, h2);
  head_kernel<<<B, 64, 0, stream>>>(h2, W3, b3, out);
}

// Round 9
// 67.239 us; speedup vs baseline: 1.1373x; 1.1373x over previous
//
#include <hip/hip_runtime.h>

#define VOCAB 100000
#define D     300
#define B     256
#define L     1000
#define H     512
#define C     5

#define D4f   (D / 4)       // 75 float4 per row
#define NR    64            // vocab ranges
#define RW    1563          // range width: 1563*64 = 100032 >= VOCAB

// ws layout (4-byte units)
// [0 .. 256000)        sorted indices (int)
// [256000 .. 272640)   off[B][65] (int)
// [272640 .. 887040)   partial[B][8][D] (float)
// [887040 .. 963840)   avg[B][D] (float)
// [963840 .. 1094912)  h1[B][H] (float)
// [1094912 .. 1225984) h2[B][H] (float)

// ---------------------------------------------------------------------------
// K0: bucket each doc's 1000 indices by vocab range, permuted so XCD x's
// 8 ranges {r : r&7==x} are contiguous: p = (r&7)*8 + (r>>3).
// ---------------------------------------------------------------------------
__global__ __launch_bounds__(256) void bucket_kernel(
    const int* __restrict__ docs, int* __restrict__ sorted,
    int* __restrict__ off) {
  const int b = blockIdx.x;
  const int t = threadIdx.x;
  __shared__ int s_idx[L];
  __shared__ int s_cnt[NR];
  __shared__ int s_base[NR];

  for (int i = t; i < L; i += 256) s_idx[i] = docs[b * L + i];
  if (t < NR) s_cnt[t] = 0;
  __syncthreads();

  for (int i = t; i < L; i += 256) {
    const int r = s_idx[i] / RW;
    const int p = ((r & 7) << 3) | (r >> 3);
    atomicAdd(&s_cnt[p], 1);
  }
  __syncthreads();

  if (t == 0) {
    int acc = 0;
    for (int k = 0; k < NR; ++k) { s_base[k] = acc; acc += s_cnt[k]; }
  }
  __syncthreads();
  if (t < NR) { off[b * 65 + t] = s_base[t]; s_cnt[t] = 0; }
  if (t == 0) off[b * 65 + NR] = L;
  __syncthreads();

  for (int i = t; i < L; i += 256) {
    const int idx = s_idx[i];
    const int r = idx / RW;
    const int p = ((r & 7) << 3) | (r >> 3);
    const int pos = s_base[p] + atomicAdd(&s_cnt[p], 1);
    sorted[b * L + pos] = idx;
  }
}

// ---------------------------------------------------------------------------
// K1: XCD-partitioned gather. grid = B*8 flat, bid = b*8 + x so bid%8 = x
// lands all blocks for vocab-octet x on XCD x (round-robin dispatch).
// Each XCD walks ranges x, x+8, ..., x+56 in order: ~1.9 MB working set,
// L2-resident, so the ~2.8x chip-wide row reuse becomes L2 hits.
// ---------------------------------------------------------------------------
__global__ __launch_bounds__(320) void gather_bucketed_kernel(
    const float* __restrict__ emb, const int* __restrict__ sorted,
    const int* __restrict__ off, float* __restrict__ partial) {
  const int bid = blockIdx.x;
  const int x = bid & 7;
  const int b = bid >> 3;
  const int t = threadIdx.x;
  const int g = t / 80;
  const int lane = t - g * 80;

  const int s = off[b * 65 + x * 8];
  const int e = off[b * 65 + x * 8 + 8];
  const int n = e - s;

  __shared__ int    sidx[256];
  __shared__ float4 sred[3][D4f];

  float ax = 0.f, ay = 0.f, az = 0.f, aw = 0.f;
  for (int base = 0; base < n; base += 256) {
    const int m = min(n - base, 256);
    __syncthreads();
    for (int i = t; i < m; i += 320) sidx[i] = sorted[b * L + s + base + i];
    __syncthreads();
    if (lane < D4f) {
#pragma unroll 4
      for (int i = g; i < m; i += 4) {
        const float4 v =
            reinterpret_cast<const float4*>(emb + (size_t)sidx[i] * D)[lane];
        ax += v.x; ay += v.y; az += v.z; aw += v.w;
      }
    }
  }
  __syncthreads();
  if (g > 0 && lane < D4f) sred[g - 1][lane] = make_float4(ax, ay, az, aw);
  __syncthreads();
  if (g == 0 && lane < D4f) {
#pragma unroll
    for (int gg = 0; gg < 3; ++gg) {
      const float4 v = sred[gg][lane];
      ax += v.x; ay += v.y; az += v.z; aw += v.w;
    }
    reinterpret_cast<float4*>(partial + (size_t)bid * D)[lane] =
        make_float4(ax, ay, az, aw);
  }
}

// ---------------------------------------------------------------------------
// K2: avg[b] = (sum of 8 octet-partials) / len[b].
// ---------------------------------------------------------------------------
__global__ __launch_bounds__(128) void avg_kernel(
    const float* __restrict__ partial, const int* __restrict__ dlen,
    float* __restrict__ avg) {
  const int b = blockIdx.x;
  const int t = threadIdx.x;
  if (t < D4f) {
    const float4* p =
        reinterpret_cast<const float4*>(partial) + (size_t)b * 8 * D4f + t;
    float4 v[8];
#pragma unroll
    for (int xx = 0; xx < 8; ++xx) v[xx] = p[xx * D4f];
    float ax = 0.f, ay = 0.f, az = 0.f, aw = 0.f;
#pragma unroll
    for (int xx = 0; xx < 8; ++xx) {
      ax += v[xx].x; ay += v[xx].y; az += v[xx].z; aw += v[xx].w;
    }
    const float inv = 1.f / (float)dlen[b];
    reinterpret_cast<float4*>(avg + (size_t)b * D)[t] =
        make_float4(ax * inv, ay * inv, az * inv, aw * inv);
  }
}

// ---------------------------------------------------------------------------
// K3: h1 = relu(avg @ W1 + b1). LDS-staged weights (proven R8 structure).
// ---------------------------------------------------------------------------
__global__ __launch_bounds__(1024) void l1_kernel(
    const float* __restrict__ avg, const float* __restrict__ W1,
    const float* __restrict__ b1, float* __restrict__ h1) {
  const int dq = blockIdx.x;
  const int cq = blockIdx.y;
  const int t = threadIdx.x;

  __shared__ float4 s_avg[16][D4f];
  __shared__ float  s_w[D][32];
  __shared__ float  s_comb[8][16][32];

  for (int o = t; o < D * 8; o += 1024) {
    const int k = o >> 3, c4 = o & 7;
    *reinterpret_cast<float4*>(&s_w[k][c4 * 4]) =
        *reinterpret_cast<const float4*>(W1 + (size_t)k * H + cq * 32 + c4 * 4);
  }
  for (int o = t; o < 16 * D4f; o += 1024) {
    const int doc = o / D4f, c4 = o - doc * D4f;
    s_avg[doc][c4] =
        reinterpret_cast<const float4*>(avg + (size_t)(dq * 16 + doc) * D)[c4];
  }
  __syncthreads();

  {
    const int doc = t & 15;
    const int cg = (t >> 4) & 7;
    const int ks = t >> 7;
    const int nf4 = (ks < 3) ? 10 : 9;
    const int o4 = (ks < 3) ? 10 * ks : 30 + 9 * (ks - 3);
    float ax = 0.f, ay = 0.f, az = 0.f, aw = 0.f;
    for (int j = 0; j < nf4; ++j) {
      const float4 x4 = s_avg[doc][o4 + j];
      const int k = 4 * (o4 + j);
      const float4 w0 = *reinterpret_cast<const float4*>(&s_w[k + 0][cg * 4]);
      const float4 w1 = *reinterpret_cast<const float4*>(&s_w[k + 1][cg * 4]);
      const float4 w2 = *reinterpret_cast<const float4*>(&s_w[k + 2][cg * 4]);
      const float4 w3 = *reinterpret_cast<const float4*>(&s_w[k + 3][cg * 4]);
      ax += x4.x * w0.x + x4.y * w1.x + x4.z * w2.x + x4.w * w3.x;
      ay += x4.x * w0.y + x4.y * w1.y + x4.z * w2.y + x4.w * w3.y;
      az += x4.x * w0.z + x4.y * w1.z + x4.z * w2.z + x4.w * w3.z;
      aw += x4.x * w0.w + x4.y * w1.w + x4.z * w2.w + x4.w * w3.w;
    }
    *reinterpret_cast<float4*>(&s_comb[ks][doc][cg * 4]) =
        make_float4(ax, ay, az, aw);
  }
  __syncthreads();

  if (t < 512) {
    const int dd = t >> 5, col = t & 31;
    float v = b1[cq * 32 + col];
#pragma unroll
    for (int s = 0; s < 8; ++s) v += s_comb[s][dd][col];
    h1[(size_t)(dq * 16 + dd) * H + cq * 32 + col] = fmaxf(v, 0.f);
  }
}

// ---------------------------------------------------------------------------
// K4: h2 = relu(h1 @ W2 + b2).
// ---------------------------------------------------------------------------
__global__ __launch_bounds__(1024) void l2_kernel(
    const float* __restrict__ h1, const float* __restrict__ W2,
    const float* __restrict__ b2, float* __restrict__ h2) {
  const int dq = blockIdx.x;
  const int cq = blockIdx.y;
  const int t = threadIdx.x;

  __shared__ float4 s_x[16][H / 4];
  __shared__ float  s_w[H][32];
  __shared__ float  s_comb[8][16][32];

  for (int o = t; o < H * 8; o += 1024) {
    const int k = o >> 3, c4 = o & 7;
    *reinterpret_cast<float4*>(&s_w[k][c4 * 4]) =
        *reinterpret_cast<const float4*>(W2 + (size_t)k * H + cq * 32 + c4 * 4);
  }
  for (int o = t; o < 16 * (H / 4); o += 1024) {
    const int doc = o >> 7, c4 = o & 127;
    s_x[doc][c4] =
        reinterpret_cast<const float4*>(h1 + (size_t)(dq * 16 + doc) * H)[c4];
  }
  __syncthreads();

  {
    const int doc = t & 15;
    const int cg = (t >> 4) & 7;
    const int ks = t >> 7;
    float ax = 0.f, ay = 0.f, az = 0.f, aw = 0.f;
    for (int j = 0; j < 16; ++j) {
      const int kk = ks * 16 + j;
      const float4 x4 = s_x[doc][kk];
      const int k = 4 * kk;
      const float4 w0 = *reinterpret_cast<const float4*>(&s_w[k + 0][cg * 4]);
      const float4 w1 = *reinterpret_cast<const float4*>(&s_w[k + 1][cg * 4]);
      const float4 w2 = *reinterpret_cast<const float4*>(&s_w[k + 2][cg * 4]);
      const float4 w3 = *reinterpret_cast<const float4*>(&s_w[k + 3][cg * 4]);
      ax += x4.x * w0.x + x4.y * w1.x + x4.z * w2.x + x4.w * w3.x;
      ay += x4.x * w0.y + x4.y * w1.y + x4.z * w2.y + x4.w * w3.y;
      az += x4.x * w0.z + x4.y * w1.z + x4.z * w2.z + x4.w * w3.z;
      aw += x4.x * w0.w + x4.y * w1.w + x4.z * w2.w + x4.w * w3.w;
    }
    *reinterpret_cast<float4*>(&s_comb[ks][doc][cg * 4]) =
        make_float4(ax, ay, az, aw);
  }
  __syncthreads();

  if (t < 512) {
    const int dd = t >> 5, col = t & 31;
    float v = b2[cq * 32 + col];
#pragma unroll
    for (int s = 0; s < 8; ++s) v += s_comb[s][dd][col];
    h2[(size_t)(dq * 16 + dd) * H + cq * 32 + col] = fmaxf(v, 0.f);
  }
}

// ---------------------------------------------------------------------------
// K5: out = h2 @ W3 + b3.
// ---------------------------------------------------------------------------
__global__ __launch_bounds__(64) void head_kernel(
    const float* __restrict__ h2, const float* __restrict__ W3,
    const float* __restrict__ b3, float* __restrict__ out) {
  const int b = blockIdx.x;
  const int l = threadIdx.x;
  float acc[C] = {0.f, 0.f, 0.f, 0.f, 0.f};
#pragma unroll
  for (int i = 0; i < H / 64; ++i) {
    const int h = i * 64 + l;
    const float v = h2[(size_t)b * H + h];
#pragma unroll
    for (int c = 0; c < C; ++c) acc[c] += v * W3[h * C + c];
  }
#pragma unroll
  for (int c = 0; c < C; ++c) {
    float a = acc[c];
#pragma unroll
    for (int off = 32; off > 0; off >>= 1) a += __shfl_down(a, off);
    if (l == 0) out[b * C + c] = a + b3[c];
  }
}

// ---------------------------------------------------------------------------
extern "C" void kernel_launch(void* const* d_in, const int* in_sizes, int n_in,
                              void* d_out, int out_size, void* d_ws,
                              size_t ws_size, hipStream_t stream) {
  const float* emb  = (const float*)d_in[0];
  const float* W1   = (const float*)d_in[1];
  const float* b1   = (const float*)d_in[2];
  const float* W2   = (const float*)d_in[3];
  const float* b2   = (const float*)d_in[4];
  const float* W3   = (const float*)d_in[5];
  const float* b3   = (const float*)d_in[6];
  const int*   docs = (const int*)d_in[7];
  const int*   dlen = (const int*)d_in[8];
  float* out = (float*)d_out;

  int*   sorted  = (int*)d_ws;
  int*   off     = sorted + B * L;                 // 256000
  float* partial = (float*)d_ws + 272640;
  float* avg     = partial + B * 8 * D;            // 887040
  float* h1      = avg + B * D;                    // 963840
  float* h2      = h1 + B * H;                     // 1094912

  bucket_kernel<<<B, 256, 0, stream>>>(docs, sorted, off);
  gather_bucketed_kernel<<<B * 8, 320, 0, stream>>>(emb, sorted, off, partial);
  avg_kernel<<<B, 128, 0, stream>>>(partial, dlen, avg);
  dim3 gl(16, 16);
  l1_kernel<<<gl, 1024, 0, stream>>>(avg, W1, b1, h1);
  l2_kernel<<<gl, 1024, 0, stream>>>(h1, W2, b2, h2);
  head_kernel<<<B, 64, 0, stream>>>(h2, W3, b3, out);
}

// Round 10
// 60.725 us; speedup vs baseline: 1.2593x; 1.1073x over previous
//
#include <hip/hip_runtime.h>

#define VOCAB 100000
#define D     300
#define B     256
#define L     1000
#define H     512
#define C     5

#define D4f    (D / 4)      // 75 float4 per row
#define NPH    8            // phases (ranges per XCD octet)
#define RW     1563         // range width: 64 ranges cover VOCAB
#define SELCAP 384          // per-doc octet capacity (mean 125, +24 sigma)

// ws layout (floats)
#define WS_PARTIAL 0                        // B*8*D = 614400
#define WS_AVG     (B * 8 * D)              // +76800
#define WS_H1      (WS_AVG + B * D)         // +131072
#define WS_H2      (WS_H1 + B * H)          // +131072 -> ~3.8 MB

// ---------------------------------------------------------------------------
// K1: phase-aligned XCD-partitioned gather.
// grid = 1024 (all co-resident, 4 blocks/CU): bid = pair*8 + x, so bid%8 = x
// puts octet-x blocks on XCD x. Each block self-buckets its 2 docs' indices
// (octet x only, by range-phase), then loops phases 0..7 IN ORDER. All
// blocks start together and per-phase work is ~equal, so each XCD's L2 sees
// one 1.9 MB range at a time -> the ~2.56x row reuse becomes L2 hits.
// ---------------------------------------------------------------------------
__global__ __launch_bounds__(320) void gather_phased_kernel(
    const float* __restrict__ emb, const int* __restrict__ docs,
    float* __restrict__ partial) {
  const int bid = blockIdx.x;
  const int x = bid & 7;            // XCD / vocab octet
  const int j = bid >> 3;           // doc pair
  const int t = threadIdx.x;
  const int g = t / 80;             // row group 0..3
  const int lane = t - g * 80;      // 0..79 (75 active)

  __shared__ int    s_raw[2][L];         // 8000 B
  __shared__ int    s_sel[2][SELCAP];    // 3072 B
  __shared__ int    s_cnt[2][NPH];
  __shared__ int    s_off[2][NPH + 1];
  __shared__ float4 sred[4][2][D4f];     // 9600 B

  // Stage both docs' raw indices.
  for (int i = t; i < 2 * L; i += 320) {
    const int dd = i < L ? 0 : 1;
    const int ii = dd ? i - L : i;
    s_raw[dd][ii] = docs[(size_t)(j * 2 + dd) * L + ii];
  }
  if (t < 2 * NPH) s_cnt[t >> 3][t & 7] = 0;
  __syncthreads();

  // Count per-phase sizes (octet x only).
  for (int i = t; i < 2 * L; i += 320) {
    const int dd = i < L ? 0 : 1;
    const int idx = s_raw[dd][dd ? i - L : i];
    const int r = idx / RW;
    if ((r & 7) == x) atomicAdd(&s_cnt[dd][r >> 3], 1);
  }
  __syncthreads();
  if (t < 2) {
    int acc = 0;
#pragma unroll
    for (int p = 0; p < NPH; ++p) { s_off[t][p] = acc; acc += s_cnt[t][p]; }
    s_off[t][NPH] = acc;
  }
  __syncthreads();
  if (t < 2 * NPH) s_cnt[t >> 3][t & 7] = 0;
  __syncthreads();

  // Scatter selected indices, bucketed by phase.
  for (int i = t; i < 2 * L; i += 320) {
    const int dd = i < L ? 0 : 1;
    const int idx = s_raw[dd][dd ? i - L : i];
    const int r = idx / RW;
    if ((r & 7) == x) {
      const int pos = s_off[dd][r >> 3] + atomicAdd(&s_cnt[dd][r >> 3], 1);
      s_sel[dd][pos] = idx;
    }
  }
  __syncthreads();

  // Phase loop: all blocks walk ranges x*8+p in the same order.
  float4 a0 = make_float4(0.f, 0.f, 0.f, 0.f);
  float4 a1 = make_float4(0.f, 0.f, 0.f, 0.f);
  if (lane < D4f) {
    for (int p = 0; p < NPH; ++p) {
      {
        const int s = s_off[0][p], e = s_off[0][p + 1];
        for (int i = s + g; i < e; i += 4) {
          const float4 v = reinterpret_cast<const float4*>(
              emb + (size_t)s_sel[0][i] * D)[lane];
          a0.x += v.x; a0.y += v.y; a0.z += v.z; a0.w += v.w;
        }
      }
      {
        const int s = s_off[1][p], e = s_off[1][p + 1];
        for (int i = s + g; i < e; i += 4) {
          const float4 v = reinterpret_cast<const float4*>(
              emb + (size_t)s_sel[1][i] * D)[lane];
          a1.x += v.x; a1.y += v.y; a1.z += v.z; a1.w += v.w;
        }
      }
    }
    sred[g][0][lane] = a0;
    sred[g][1][lane] = a1;
  }
  __syncthreads();

  if (t < 2 * D4f) {
    const int dd = t / D4f, c4 = t - dd * D4f;
    float ax = 0.f, ay = 0.f, az = 0.f, aw = 0.f;
#pragma unroll
    for (int gg = 0; gg < 4; ++gg) {
      const float4 v = sred[gg][dd][c4];
      ax += v.x; ay += v.y; az += v.z; aw += v.w;
    }
    reinterpret_cast<float4*>(partial +
                              (size_t)((j * 2 + dd) * 8 + x) * D)[c4] =
        make_float4(ax, ay, az, aw);
  }
}

// ---------------------------------------------------------------------------
// K2: avg[b] = (sum of 8 octet-partials) / len[b].
// ---------------------------------------------------------------------------
__global__ __launch_bounds__(128) void avg_kernel(
    const float* __restrict__ partial, const int* __restrict__ dlen,
    float* __restrict__ avg) {
  const int b = blockIdx.x;
  const int t = threadIdx.x;
  if (t < D4f) {
    const float4* p =
        reinterpret_cast<const float4*>(partial) + (size_t)b * 8 * D4f + t;
    float4 v[8];
#pragma unroll
    for (int xx = 0; xx < 8; ++xx) v[xx] = p[xx * D4f];
    float ax = 0.f, ay = 0.f, az = 0.f, aw = 0.f;
#pragma unroll
    for (int xx = 0; xx < 8; ++xx) {
      ax += v[xx].x; ay += v[xx].y; az += v[xx].z; aw += v[xx].w;
    }
    const float inv = 1.f / (float)dlen[b];
    reinterpret_cast<float4*>(avg + (size_t)b * D)[t] =
        make_float4(ax * inv, ay * inv, az * inv, aw * inv);
  }
}

// ---------------------------------------------------------------------------
// K3: h1 = relu(avg @ W1 + b1). LDS-staged weights (proven structure).
// ---------------------------------------------------------------------------
__global__ __launch_bounds__(1024) void l1_kernel(
    const float* __restrict__ avg, const float* __restrict__ W1,
    const float* __restrict__ b1, float* __restrict__ h1) {
  const int dq = blockIdx.x;
  const int cq = blockIdx.y;
  const int t = threadIdx.x;

  __shared__ float4 s_avg[16][D4f];
  __shared__ float  s_w[D][32];
  __shared__ float  s_comb[8][16][32];

  for (int o = t; o < D * 8; o += 1024) {
    const int k = o >> 3, c4 = o & 7;
    *reinterpret_cast<float4*>(&s_w[k][c4 * 4]) =
        *reinterpret_cast<const float4*>(W1 + (size_t)k * H + cq * 32 + c4 * 4);
  }
  for (int o = t; o < 16 * D4f; o += 1024) {
    const int doc = o / D4f, c4 = o - doc * D4f;
    s_avg[doc][c4] =
        reinterpret_cast<const float4*>(avg + (size_t)(dq * 16 + doc) * D)[c4];
  }
  __syncthreads();

  {
    const int doc = t & 15;
    const int cg = (t >> 4) & 7;
    const int ks = t >> 7;
    const int nf4 = (ks < 3) ? 10 : 9;
    const int o4 = (ks < 3) ? 10 * ks : 30 + 9 * (ks - 3);
    float ax = 0.f, ay = 0.f, az = 0.f, aw = 0.f;
    for (int j = 0; j < nf4; ++j) {
      const float4 x4 = s_avg[doc][o4 + j];
      const int k = 4 * (o4 + j);
      const float4 w0 = *reinterpret_cast<const float4*>(&s_w[k + 0][cg * 4]);
      const float4 w1 = *reinterpret_cast<const float4*>(&s_w[k + 1][cg * 4]);
      const float4 w2 = *reinterpret_cast<const float4*>(&s_w[k + 2][cg * 4]);
      const float4 w3 = *reinterpret_cast<const float4*>(&s_w[k + 3][cg * 4]);
      ax += x4.x * w0.x + x4.y * w1.x + x4.z * w2.x + x4.w * w3.x;
      ay += x4.x * w0.y + x4.y * w1.y + x4.z * w2.y + x4.w * w3.y;
      az += x4.x * w0.z + x4.y * w1.z + x4.z * w2.z + x4.w * w3.z;
      aw += x4.x * w0.w + x4.y * w1.w + x4.z * w2.w + x4.w * w3.w;
    }
    *reinterpret_cast<float4*>(&s_comb[ks][doc][cg * 4]) =
        make_float4(ax, ay, az, aw);
  }
  __syncthreads();

  if (t < 512) {
    const int dd = t >> 5, col = t & 31;
    float v = b1[cq * 32 + col];
#pragma unroll
    for (int s = 0; s < 8; ++s) v += s_comb[s][dd][col];
    h1[(size_t)(dq * 16 + dd) * H + cq * 32 + col] = fmaxf(v, 0.f);
  }
}

// ---------------------------------------------------------------------------
// K4: h2 = relu(h1 @ W2 + b2).
// ---------------------------------------------------------------------------
__global__ __launch_bounds__(1024) void l2_kernel(
    const float* __restrict__ h1, const float* __restrict__ W2,
    const float* __restrict__ b2, float* __restrict__ h2) {
  const int dq = blockIdx.x;
  const int cq = blockIdx.y;
  const int t = threadIdx.x;

  __shared__ float4 s_x[16][H / 4];
  __shared__ float  s_w[H][32];
  __shared__ float  s_comb[8][16][32];

  for (int o = t; o < H * 8; o += 1024) {
    const int k = o >> 3, c4 = o & 7;
    *reinterpret_cast<float4*>(&s_w[k][c4 * 4]) =
        *reinterpret_cast<const float4*>(W2 + (size_t)k * H + cq * 32 + c4 * 4);
  }
  for (int o = t; o < 16 * (H / 4); o += 1024) {
    const int doc = o >> 7, c4 = o & 127;
    s_x[doc][c4] =
        reinterpret_cast<const float4*>(h1 + (size_t)(dq * 16 + doc) * H)[c4];
  }
  __syncthreads();

  {
    const int doc = t & 15;
    const int cg = (t >> 4) & 7;
    const int ks = t >> 7;
    float ax = 0.f, ay = 0.f, az = 0.f, aw = 0.f;
    for (int j = 0; j < 16; ++j) {
      const int kk = ks * 16 + j;
      const float4 x4 = s_x[doc][kk];
      const int k = 4 * kk;
      const float4 w0 = *reinterpret_cast<const float4*>(&s_w[k + 0][cg * 4]);
      const float4 w1 = *reinterpret_cast<const float4*>(&s_w[k + 1][cg * 4]);
      const float4 w2 = *reinterpret_cast<const float4*>(&s_w[k + 2][cg * 4]);
      const float4 w3 = *reinterpret_cast<const float4*>(&s_w[k + 3][cg * 4]);
      ax += x4.x * w0.x + x4.y * w1.x + x4.z * w2.x + x4.w * w3.x;
      ay += x4.x * w0.y + x4.y * w1.y + x4.z * w2.y + x4.w * w3.y;
      az += x4.x * w0.z + x4.y * w1.z + x4.z * w2.z + x4.w * w3.z;
      aw += x4.x * w0.w + x4.y * w1.w + x4.z * w2.w + x4.w * w3.w;
    }
    *reinterpret_cast<float4*>(&s_comb[ks][doc][cg * 4]) =
        make_float4(ax, ay, az, aw);
  }
  __syncthreads();

  if (t < 512) {
    const int dd = t >> 5, col = t & 31;
    float v = b2[cq * 32 + col];
#pragma unroll
    for (int s = 0; s < 8; ++s) v += s_comb[s][dd][col];
    h2[(size_t)(dq * 16 + dd) * H + cq * 32 + col] = fmaxf(v, 0.f);
  }
}

// ---------------------------------------------------------------------------
// K5: out = h2 @ W3 + b3.
// ---------------------------------------------------------------------------
__global__ __launch_bounds__(64) void head_kernel(
    const float* __restrict__ h2, const float* __restrict__ W3,
    const float* __restrict__ b3, float* __restrict__ out) {
  const int b = blockIdx.x;
  const int l = threadIdx.x;
  float acc[C] = {0.f, 0.f, 0.f, 0.f, 0.f};
#pragma unroll
  for (int i = 0; i < H / 64; ++i) {
    const int h = i * 64 + l;
    const float v = h2[(size_t)b * H + h];
#pragma unroll
    for (int c = 0; c < C; ++c) acc[c] += v * W3[h * C + c];
  }
#pragma unroll
  for (int c = 0; c < C; ++c) {
    float a = acc[c];
#pragma unroll
    for (int off = 32; off > 0; off >>= 1) a += __shfl_down(a, off);
    if (l == 0) out[b * C + c] = a + b3[c];
  }
}

// ---------------------------------------------------------------------------
extern "C" void kernel_launch(void* const* d_in, const int* in_sizes, int n_in,
                              void* d_out, int out_size, void* d_ws,
                              size_t ws_size, hipStream_t stream) {
  const float* emb  = (const float*)d_in[0];
  const float* W1   = (const float*)d_in[1];
  const float* b1   = (const float*)d_in[2];
  const float* W2   = (const float*)d_in[3];
  const float* b2   = (const float*)d_in[4];
  const float* W3   = (const float*)d_in[5];
  const float* b3   = (const float*)d_in[6];
  const int*   docs = (const int*)d_in[7];
  const int*   dlen = (const int*)d_in[8];
  float* out = (float*)d_out;

  float* ws = (float*)d_ws;
  float* partial = ws + WS_PARTIAL;
  float* avg = ws + WS_AVG;
  float* h1  = ws + WS_H1;
  float* h2  = ws + WS_H2;

  gather_phased_kernel<<<B / 2 * 8, 320, 0, stream>>>(emb, docs, partial);
  avg_kernel<<<B, 128, 0, stream>>>(partial, dlen, avg);
  dim3 gl(16, 16);
  l1_kernel<<<gl, 1024, 0, stream>>>(avg, W1, b1, h1);
  l2_kernel<<<gl, 1024, 0, stream>>>(h1, W2, b2, h2);
  head_kernel<<<B, 64, 0, stream>>>(h2, W3, b3, out);
}